// Round 7
// baseline (1414.291 us; speedup 1.0000x reference)
//
#include <hip/hip_runtime.h>
#include <cstdint>
#include <cstddef>

#define B_  4
#define S_  4096
#define H_  1024
#define NH_ 16
#define M_  (B_*S_)   // 16384 rows

typedef __bf16 bf16x8 __attribute__((ext_vector_type(8)));
typedef float  f32x4  __attribute__((ext_vector_type(4)));

__device__ __forceinline__ unsigned short f2b(float f) {
  union { float f; unsigned u; } v; v.f = f;
  unsigned r = v.u + 0x7FFFu + ((v.u >> 16) & 1u);
  return (unsigned short)(r >> 16);
}
__device__ __forceinline__ float b2f(unsigned short u) {
  union { unsigned u; float f; } v; v.u = ((unsigned)u) << 16;
  return v.f;
}

#define GLD16(g, l) __builtin_amdgcn_global_load_lds( \
    (const __attribute__((address_space(1))) void*)(g), \
    (__attribute__((address_space(3))) void*)(l), 16, 0, 0)

#define VM0()  asm volatile("s_waitcnt vmcnt(0)" ::: "memory")
#define BAR()  do { asm volatile("" ::: "memory"); __builtin_amdgcn_s_barrier(); \
                    asm volatile("" ::: "memory"); } while (0)

// ---------------------------------------------------------------- casts
__global__ void cast_f32_bf16(const float* __restrict__ src,
                              unsigned short* __restrict__ dst, int n4) {
  int i = blockIdx.x * blockDim.x + threadIdx.x;
  if (i >= n4) return;
  float4 f = reinterpret_cast<const float4*>(src)[i];
  ushort4 o;
  o.x = f2b(f.x); o.y = f2b(f.y); o.z = f2b(f.z); o.w = f2b(f.w);
  reinterpret_cast<ushort4*>(dst)[i] = o;
}

// 4 weights (1M elems each) -> one concatenated bf16 buffer [4][1024][1024]
__global__ void cast_w4(const float* __restrict__ w0, const float* __restrict__ w1,
                        const float* __restrict__ w2, const float* __restrict__ w3,
                        unsigned short* __restrict__ dst) {
  int i = blockIdx.x * blockDim.x + threadIdx.x;      // float4 index, 1M total
  int w = i >> 18, j = i & 0x3FFFF;
  const float* src = (w == 0) ? w0 : (w == 1) ? w1 : (w == 2) ? w2 : w3;
  float4 f = reinterpret_cast<const float4*>(src)[j];
  ushort4 o;
  o.x = f2b(f.x); o.y = f2b(f.y); o.z = f2b(f.z); o.w = f2b(f.w);
  reinterpret_cast<ushort4*>(dst)[i] = o;
}

// ---------------------------------------------------------------- 256x256 GEMM
// C[M,N] = A[M,1024] * Bt[N,1024]^T, BK=32, 512 thr = 8 waves (2M x 4N).
// 64 KiB LDS double-buffer -> 2 blocks/CU: cross-block overlap hides barrier/
// latency stalls (m97 mechanism). T3 minimum-2-phase tile loop:
//   { stage 4 halves of tile t+1 -> buf^1; 12 ds_reads; 32 MFMA; vmcnt(0); BAR }
// No intra-tile barriers (all reads from cb, all writes to nb; boundary BAR
// plus per-wave VM0 certifies everything).
// Swizzle (rows are 64B): read chunk = fq ^ ((fr>>1)&3); staging source
// pre-swizzled col chunk = (tid&3) ^ ((tid>>3)&3). Uniform 8 lanes/16B slot.
// Epilogue: regs -> swizzled LDS (<=64KB passes) -> coalesced 16B stores.
// MODE 0: N=3072, bf16 out routed to Q/K/V with ELU on Q,K.
// MODE 1: N=1024, Bt is per-batch [4][1024][1024], f32 out.
template<int MODE>
__global__ __launch_bounds__(512, 4) void gemm256(
    const unsigned short* __restrict__ A_,
    const unsigned short* __restrict__ Bt_,
    void* __restrict__ out) {
  __shared__ __align__(16) unsigned short LDS[2][2][8192];  // [dbuf][A|B][256*32] = 64KB

  const int NTN = (MODE == 0) ? 12 : 4;
  const int nx  = gridDim.x >> 3;
  const int b2  = (blockIdx.x & 7) * nx + (blockIdx.x >> 3);  // XCD swizzle (grid%8==0)
  const int tileM = (b2 / NTN) << 8;
  const int tileN = (b2 % NTN) << 8;

  const unsigned short* Bt_e =
      (MODE == 1) ? (Bt_ + ((size_t)(tileM >> 12) << 20)) : Bt_;

  const int tid  = threadIdx.x;
  const int lane = tid & 63, wv = tid >> 6;
  const int wmi  = wv >> 2;     // 0..1
  const int wni  = wv & 3;      // 0..3
  const int fr   = lane & 15, fq = lane >> 4;

  // staging: 4 gload_lds per tile (A0,A1,B0,B1 halves of 8KB each).
  // thread covers 16B chunk tid of its half: row = tid>>2, pre-swz col chunk:
  const int ssr = tid >> 2;
  const int ssc = (tid & 3) ^ ((tid >> 3) & 3);
  // ds_read swizzled chunk offset (elems), constant per thread:
  const int xk = (fq ^ ((fr >> 1) & 3)) * 8;

#define STG(NB, ARR, HM, SRC, RB, TT) \
    GLD16((SRC) + (size_t)((RB) + (HM)*128 + ssr) * 1024 + (TT)*32 + ssc*8, \
          &LDS[NB][ARR][(HM)*4096 + wv*512])

#define READA(CB, MQ, DST) do {                                                 \
    _Pragma("unroll")                                                           \
    for (int m = 0; m < 4; m++) {                                               \
      int r = (MQ)*128 + wmi*64 + m*16 + fr;                                    \
      DST[m] = *(const bf16x8*)&LDS[CB][0][r*32 + xk];                          \
    }                                                                           \
  } while (0)

#define READB(CB, NQ, DST) do {                                                 \
    _Pragma("unroll")                                                           \
    for (int n = 0; n < 2; n++) {                                               \
      int r = (NQ)*128 + wni*32 + n*16 + fr;                                    \
      DST[n] = *(const bf16x8*)&LDS[CB][1][r*32 + xk];                          \
    }                                                                           \
  } while (0)

#define MMQ(MQ, NQ, AS, BS) do {                                                \
    __builtin_amdgcn_s_setprio(1);                                              \
    _Pragma("unroll")                                                           \
    for (int m = 0; m < 4; m++)                                                 \
      _Pragma("unroll")                                                         \
      for (int n = 0; n < 2; n++)                                               \
        acc[MQ][NQ][m][n] = __builtin_amdgcn_mfma_f32_16x16x32_bf16(            \
            AS[m], BS[n], acc[MQ][NQ][m][n], 0, 0, 0);                          \
    __builtin_amdgcn_s_setprio(0);                                              \
  } while (0)

  f32x4 zero = {0.f, 0.f, 0.f, 0.f};
  f32x4 acc[2][2][4][2];
#pragma unroll
  for (int a = 0; a < 2; a++)
#pragma unroll
    for (int b = 0; b < 2; b++)
#pragma unroll
      for (int m = 0; m < 4; m++)
#pragma unroll
        for (int n = 0; n < 2; n++) acc[a][b][m][n] = zero;

  bf16x8 aA[4], aB[4], bA[2], bB[2];

  // prologue: tile 0 into buf 0
  STG(0, 0, 0, A_,   tileM, 0);
  STG(0, 0, 1, A_,   tileM, 0);
  STG(0, 1, 0, Bt_e, tileN, 0);
  STG(0, 1, 1, Bt_e, tileN, 0);
  VM0();
  BAR();

  int cb = 0;
#pragma unroll 1
  for (int t = 0; t < 32; ++t) {
    const int nb = cb ^ 1;
    if (t < 31) {
      STG(nb, 0, 0, A_,   tileM, t + 1);
      STG(nb, 1, 0, Bt_e, tileN, t + 1);
      STG(nb, 1, 1, Bt_e, tileN, t + 1);
      STG(nb, 0, 1, A_,   tileM, t + 1);
    }
    READA(cb, 0, aA); READB(cb, 0, bA); READB(cb, 1, bB); READA(cb, 1, aB);
    MMQ(0, 0, aA, bA);
    MMQ(0, 1, aA, bB);
    MMQ(1, 1, aB, bB);
    MMQ(1, 0, aB, bA);
    VM0();
    BAR();
    cb = nb;
  }

  // ---------------- epilogue: LDS-staged coalesced stores (64KB passes) ----
  if (MODE == 0) {
    unsigned short* Ep = &LDS[0][0][0];           // [128][256] u16 = 64KB
    const int reg = tileN >> 10;                  // 0=Q,1=K,2=V (uniform)
    const bool doELU = (reg < 2);
    unsigned short* outp = (unsigned short*)out + (size_t)reg * M_ * H_;
    const int lcbase = tileN & 1023;
#pragma unroll
    for (int h = 0; h < 2; h++) {                 // M-halves (mq == h)
      BAR();
#pragma unroll
      for (int nq = 0; nq < 2; nq++)
#pragma unroll
        for (int m = 0; m < 4; m++)
#pragma unroll
          for (int n = 0; n < 2; n++)
#pragma unroll
            for (int r = 0; r < 4; r++) {
              int row = wmi * 64 + m * 16 + fq * 4 + r;     // 0..127
              int col = nq * 128 + wni * 32 + n * 16 + fr;
              float v = acc[h][nq][m][n][r];
              if (doELU) v = v > 0.f ? v : (expf(v) - 1.f);
              Ep[row * 256 + (col ^ ((row & 7) << 3))] = f2b(v);
            }
      BAR();
#pragma unroll
      for (int it = 0; it < 8; it++) {
        int g = it * 512 + tid;        // 4096 chunks of 16B (128 rows x 32)
        int row = g >> 5, col = (g & 31) * 8;
        bf16x8 val = *(const bf16x8*)&Ep[row * 256 + (col ^ ((row & 7) << 3))];
        *(bf16x8*)&outp[(size_t)(tileM + h * 128 + row) * H_ + lcbase + col] = val;
      }
    }
  } else {
    float* Ef = (float*)&LDS[0][0][0];            // [64][256] f32 = 64KB
#pragma unroll
    for (int q = 0; q < 4; q++) {                 // rows [q*64, q*64+64)
      BAR();
      if (wmi == (q & 1)) {
        const int mq = q >> 1;
#pragma unroll
        for (int nq = 0; nq < 2; nq++)
#pragma unroll
          for (int m = 0; m < 4; m++)
#pragma unroll
            for (int n = 0; n < 2; n++)
#pragma unroll
              for (int r = 0; r < 4; r++) {
                int lr  = m * 16 + fq * 4 + r;    // 0..63
                int col = nq * 128 + wni * 32 + n * 16 + fr;
                Ef[lr * 256 + (col ^ ((lr & 7) << 2))] = acc[mq][nq][m][n][r];
              }
      }
      BAR();
#pragma unroll
      for (int it = 0; it < 8; it++) {
        int g = it * 512 + tid;        // 4096 chunks of 16B (64 rows x 64)
        int row = g >> 6, c = (g & 63) * 4;
        f32x4 val = *(const f32x4*)&Ef[row * 256 + (c ^ ((row & 7) << 2))];
        *(f32x4*)&((float*)out)[(size_t)(tileM + q * 64 + row) * H_ + tileN + c] = val;
      }
    }
  }
#undef MMQ
#undef READB
#undef READA
#undef STG
}

// ---------------------------------------------------------------- stage 2: KV partials
// kvp[bh*8+ch][d][e] = sum_{s in 512-chunk} K[b,s,h,d] * V[b,s,h,e]
__global__ __launch_bounds__(256) void kv_partial(
    const unsigned short* __restrict__ Kb,
    const unsigned short* __restrict__ Vb,
    float* __restrict__ kvp) {
  __shared__ __align__(16) unsigned short kt[32 * 64];
  __shared__ __align__(16) unsigned short vt[32 * 64];
  const int bh = blockIdx.x >> 3;
  const int ch = blockIdx.x & 7;
  const int b  = bh >> 4, h = bh & 15;
  const int t  = threadIdx.x;
  const int rr = t >> 3;
  const int cc = (t & 7) * 8;
  const int d0 = (t >> 4) * 4;
  const int e0 = (t & 15) * 4;

  float acc[4][4] = {};
  for (int s0 = ch * 512; s0 < ch * 512 + 512; s0 += 32) {
    size_t g = (size_t)(b * S_ + s0 + rr) * H_ + h * 64 + cc;
    *reinterpret_cast<uint4*>(&kt[rr * 64 + cc]) = *reinterpret_cast<const uint4*>(Kb + g);
    *reinterpret_cast<uint4*>(&vt[rr * 64 + cc]) = *reinterpret_cast<const uint4*>(Vb + g);
    __syncthreads();
#pragma unroll 4
    for (int ss = 0; ss < 32; ss++) {
      ushort4 k4 = *reinterpret_cast<const ushort4*>(&kt[ss * 64 + d0]);
      ushort4 v4 = *reinterpret_cast<const ushort4*>(&vt[ss * 64 + e0]);
      float kf[4] = {b2f(k4.x), b2f(k4.y), b2f(k4.z), b2f(k4.w)};
      float vf[4] = {b2f(v4.x), b2f(v4.y), b2f(v4.z), b2f(v4.w)};
#pragma unroll
      for (int i = 0; i < 4; i++)
#pragma unroll
        for (int j = 0; j < 4; j++) acc[i][j] += kf[i] * vf[j];
    }
    __syncthreads();
  }
  float* outp = kvp + (size_t)blockIdx.x * 4096;
#pragma unroll
  for (int i = 0; i < 4; i++)
#pragma unroll
    for (int j = 0; j < 4; j++) outp[(d0 + i) * 64 + e0 + j] = acc[i][j];
}

// reduce 8 partials -> KV[bh][d][e] bf16 (row-major d)
__global__ __launch_bounds__(256) void kv_reduce(
    const float* __restrict__ kvp, unsigned short* __restrict__ KVb) {
  const int bh = blockIdx.x;
#pragma unroll
  for (int i = 0; i < 16; i++) {
    int idx = threadIdx.x + i * 256;
    float s = 0.f;
#pragma unroll
    for (int ch = 0; ch < 8; ch++) s += kvp[(size_t)(bh * 8 + ch) * 4096 + idx];
    KVb[(size_t)bh * 4096 + idx] = f2b(s);
  }
}

// ---------------------------------------------------------------- merged weight
// MbT[b][n][h*64+d] = sum_e KV[b,h][d][e] * Wo[n][h*64+e]   (Bt layout for final GEMM)
__global__ __launch_bounds__(256) void merge_m(
    const unsigned short* __restrict__ KVb,
    const unsigned short* __restrict__ Wob,
    unsigned short* __restrict__ MbT) {
  const int bh = blockIdx.x >> 2;
  const int nc = blockIdx.x & 3;
  const int b  = bh >> 4, h = bh & 15;
  const int lane = threadIdx.x & 63, wv = threadIdx.x >> 6;
  const int fr = lane & 15, fq = lane >> 4;
  const int ncb = nc * 256 + wv * 64;

  f32x4 zero = {0.f, 0.f, 0.f, 0.f};
  f32x4 acc[4][4];
#pragma unroll
  for (int i = 0; i < 4; i++)
#pragma unroll
    for (int j = 0; j < 4; j++) acc[i][j] = zero;

#pragma unroll
  for (int kk = 0; kk < 2; kk++) {
    bf16x8 af[4], bvv[4];
#pragma unroll
    for (int i = 0; i < 4; i++)
      af[i] = *(const bf16x8*)&KVb[(size_t)bh * 4096 + (i * 16 + fr) * 64 + kk * 32 + fq * 8];
#pragma unroll
    for (int j = 0; j < 4; j++)
      bvv[j] = *(const bf16x8*)&Wob[(size_t)(ncb + j * 16 + fr) * 1024 + h * 64 + kk * 32 + fq * 8];
#pragma unroll
    for (int i = 0; i < 4; i++)
#pragma unroll
      for (int j = 0; j < 4; j++)
        acc[i][j] = __builtin_amdgcn_mfma_f32_16x16x32_bf16(af[i], bvv[j], acc[i][j], 0, 0, 0);
  }
#pragma unroll
  for (int i = 0; i < 4; i++)
#pragma unroll
    for (int j = 0; j < 4; j++)
#pragma unroll
      for (int r = 0; r < 4; r++) {
        int n = ncb + j * 16 + fr;
        int k = h * 64 + i * 16 + fq * 4 + r;
        MbT[((size_t)b << 20) + (size_t)n * 1024 + k] = f2b(acc[i][j][r]);
      }
}

// ---------------------------------------------------------------- launch
extern "C" void kernel_launch(void* const* d_in, const int* in_sizes, int n_in,
                              void* d_out, int out_size, void* d_ws, size_t ws_size,
                              hipStream_t stream) {
  (void)in_sizes; (void)n_in; (void)out_size; (void)ws_size;
  const float* X  = (const float*)d_in[0];
  const float* Wq = (const float*)d_in[1];
  const float* Wk = (const float*)d_in[2];
  const float* Wv = (const float*)d_in[3];
  const float* Wo = (const float*)d_in[4];

  char*  ws  = (char*)d_ws;
  size_t off = 0;
  auto alloc = [&](size_t bytes) -> char* {
    char* p = ws + off;
    off += (bytes + 255) & ~(size_t)255;
    return p;
  };
  unsigned short* Xb   = (unsigned short*)alloc((size_t)M_ * H_ * 2);
  unsigned short* Wcat = (unsigned short*)alloc((size_t)4 * H_ * H_ * 2);  // Wq|Wk|Wv|Wo
  unsigned short* QKVb = (unsigned short*)alloc((size_t)3 * M_ * H_ * 2);  // Q|K|V
  float*          kvp  = (float*)alloc((size_t)64 * 8 * 4096 * 4);
  unsigned short* KVb  = (unsigned short*)alloc((size_t)64 * 4096 * 2);
  unsigned short* MbT  = (unsigned short*)alloc((size_t)4 * H_ * H_ * 2);

  unsigned short* Qb = QKVb;
  unsigned short* Kb = QKVb + (size_t)M_ * H_;
  unsigned short* Vb = QKVb + (size_t)2 * M_ * H_;
  unsigned short* Wob = Wcat + (size_t)3 * H_ * H_;

  cast_f32_bf16<<<(M_ * H_) / 1024, 256, 0, stream>>>(X, Xb, (M_ * H_) / 4);
  cast_w4<<<(4 * H_ * H_) / 1024, 256, 0, stream>>>(Wq, Wk, Wv, Wo, Wcat);

  gemm256<0><<<768, 512, 0, stream>>>(Xb, Wcat, QKVb);   // Q,K,V (ELU on Q,K)

  kv_partial<<<512, 256, 0, stream>>>(Kb, Vb, kvp);
  kv_reduce<<<64, 256, 0, stream>>>(kvp, KVb);
  merge_m<<<256, 256, 0, stream>>>(KVb, Wob, MbT);

  gemm256<1><<<256, 512, 0, stream>>>(Qb, MbT, (float*)d_out);  // Y = Q @ M[b]^T
}

// Round 9
// 266.207 us; speedup vs baseline: 5.3128x; 5.3128x over previous
//
#include <hip/hip_runtime.h>
#include <cstdint>
#include <cstddef>

#define B_  4
#define S_  4096
#define H_  1024
#define NH_ 16
#define M_  (B_*S_)   // 16384 rows

typedef __bf16 bf16x8 __attribute__((ext_vector_type(8)));
typedef float  f32x4  __attribute__((ext_vector_type(4)));

__device__ __forceinline__ unsigned short f2b(float f) {
  union { float f; unsigned u; } v; v.f = f;
  unsigned r = v.u + 0x7FFFu + ((v.u >> 16) & 1u);
  return (unsigned short)(r >> 16);
}
__device__ __forceinline__ float b2f(unsigned short u) {
  union { unsigned u; float f; } v; v.u = ((unsigned)u) << 16;
  return v.f;
}

#define GLD16(g, l) __builtin_amdgcn_global_load_lds( \
    (const __attribute__((address_space(1))) void*)(g), \
    (__attribute__((address_space(3))) void*)(l), 16, 0, 0)

#define VM0()  asm volatile("s_waitcnt vmcnt(0)" ::: "memory")
#define VM4()  asm volatile("s_waitcnt vmcnt(4)" ::: "memory")
#define BAR()  do { asm volatile("" ::: "memory"); __builtin_amdgcn_s_barrier(); \
                    asm volatile("" ::: "memory"); } while (0)

// ---------------------------------------------------------------- casts
__global__ void cast_f32_bf16(const float* __restrict__ src,
                              unsigned short* __restrict__ dst, int n4) {
  int i = blockIdx.x * blockDim.x + threadIdx.x;
  if (i >= n4) return;
  float4 f = reinterpret_cast<const float4*>(src)[i];
  ushort4 o;
  o.x = f2b(f.x); o.y = f2b(f.y); o.z = f2b(f.z); o.w = f2b(f.w);
  reinterpret_cast<ushort4*>(dst)[i] = o;
}

// 4 weights (1M elems each) -> one concatenated bf16 buffer [4][1024][1024]
__global__ void cast_w4(const float* __restrict__ w0, const float* __restrict__ w1,
                        const float* __restrict__ w2, const float* __restrict__ w3,
                        unsigned short* __restrict__ dst) {
  int i = blockIdx.x * blockDim.x + threadIdx.x;      // float4 index, 1M total
  int w = i >> 18, j = i & 0x3FFFF;
  const float* src = (w == 0) ? w0 : (w == 1) ? w1 : (w == 2) ? w2 : w3;
  float4 f = reinterpret_cast<const float4*>(src)[j];
  ushort4 o;
  o.x = f2b(f.x); o.y = f2b(f.y); o.z = f2b(f.z); o.w = f2b(f.w);
  reinterpret_cast<ushort4*>(dst)[i] = o;
}

// ---------------------------------------------------------------- 256x256 GEMM
// m201-style 8-phase: C[M,N] = A[M,1024]*Bt[N,1024]^T, BK=64, 512 thr,
// 8 waves 2M x 4N, per-wave output 128x64 (wave owns A-half wmi, B-half wni>>1).
// LDS [dbuf][A|B][half][128x64] = 128 KiB. Per K-tile, 4 quadrant phases with
// SEPARATE operand register sets (a0,a1,b0,b1 — q3 reuses a1,b0, both live):
//   q0 (mq0,nq0): read a0,b0 (12 ds) | stage A0(t+1)->buf^1 | BAR | MFMA | BAR
//   q1 (mq0,nq1): read b1    ( 4 ds) | stage A1(t+1)->buf^1 | BAR | MFMA | BAR
//   q2 (mq1,nq1): read a1    ( 8 ds) | stage B0(t+2)->buf   | BAR | MFMA | BAR
//   q3 (mq1,nq0): (no reads)         | stage B1(t+2)->buf | vmcnt(4) | BAR | MFMA | BAR
// WAR safety: phase reads are consumed before the phase's closing barrier
// (MFMA waits lgkmcnt before use), so B(t+2) staging at q2 can't corrupt
// q0/q1's B(t) reads. vmcnt(4) certifies {A(t+1),B(t+1)}, leaves B(t+2) in
// flight; certify-to-read lag >= 2 phases.
// LDS swizzle: 16B-chunk ^= (row&7) on stage-source and reads (0 conflicts).
// MODE 0: N=3072, bf16 out -> Q/K/V with ELU on Q,K. MODE 1: N=1024,
// Bt per-batch [4][1024][1024], f32 out.
template<int MODE>
__global__ __launch_bounds__(512, 2) void gemm256(
    const unsigned short* __restrict__ A_,
    const unsigned short* __restrict__ Bt_,
    void* __restrict__ out) {
  __shared__ __align__(16) unsigned short LDS[2][2][2][8192];  // 128 KiB

  const int NTN = (MODE == 0) ? 12 : 4;
  const int nx  = gridDim.x >> 3;
  const int b2  = (blockIdx.x & 7) * nx + (blockIdx.x >> 3);  // XCD swizzle (grid%8==0)
  const int tileM = (b2 / NTN) << 8;
  const int tileN = (b2 % NTN) << 8;

  const unsigned short* Bt_e =
      (MODE == 1) ? (Bt_ + ((size_t)(tileM >> 12) << 20)) : Bt_;

  const int tid  = threadIdx.x;
  const int lane = tid & 63, wv = tid >> 6;
  const int wmi  = wv >> 2;     // A-half owner (rows wmi*128..+127)
  const int wni  = wv & 3;      // 64-col slice; B-half = wni>>1
  const int hb   = wni >> 1;
  const int fr   = lane & 15, fq = lane >> 4;

  // staging: half = 128 rows x 64 cols = 16KB = 2 gload16/thread.
  const int sr0 = tid >> 3,          sc0 = (tid & 7) ^ (sr0 & 7);
  const int sr1 = (tid + 512) >> 3,  sc1 = (tid & 7) ^ (sr1 & 7);

#define STG(DB, ARR, HM, SRC, RB, TT) do {                                      \
    GLD16((SRC) + (size_t)((RB) + (HM)*128 + sr0) * 1024 + (TT)*64 + sc0*8,     \
          &LDS[DB][ARR][HM][wv*512]);                                           \
    GLD16((SRC) + (size_t)((RB) + (HM)*128 + sr1) * 1024 + (TT)*64 + sc1*8,     \
          &LDS[DB][ARR][HM][4096 + wv*512]);                                    \
  } while (0)

#define RDA(CB, MQ, DST) do {                                                   \
    _Pragma("unroll")                                                           \
    for (int m = 0; m < 4; m++) {                                               \
      int rr = (MQ)*64 + m*16 + fr;                                             \
      DST[m][0] = *(const bf16x8*)&LDS[CB][0][wmi][rr*64 + ((fq   ) ^ (rr&7))*8];\
      DST[m][1] = *(const bf16x8*)&LDS[CB][0][wmi][rr*64 + ((4+fq ) ^ (rr&7))*8];\
    }                                                                           \
  } while (0)

#define RDB(CB, NQ, DST) do {                                                   \
    _Pragma("unroll")                                                           \
    for (int n = 0; n < 2; n++) {                                               \
      int rb = (wni & 1)*64 + (NQ)*32 + n*16 + fr;                              \
      DST[n][0] = *(const bf16x8*)&LDS[CB][1][hb][rb*64 + ((fq   ) ^ (rb&7))*8];\
      DST[n][1] = *(const bf16x8*)&LDS[CB][1][hb][rb*64 + ((4+fq ) ^ (rb&7))*8];\
    }                                                                           \
  } while (0)

#define MMQ(MQ, NQ, AS, BS) do {                                                \
    __builtin_amdgcn_s_setprio(1);                                              \
    _Pragma("unroll")                                                           \
    for (int m = 0; m < 4; m++)                                                 \
      _Pragma("unroll")                                                         \
      for (int n = 0; n < 2; n++) {                                             \
        acc[MQ][NQ][m][n] = __builtin_amdgcn_mfma_f32_16x16x32_bf16(            \
            AS[m][0], BS[n][0], acc[MQ][NQ][m][n], 0, 0, 0);                    \
        acc[MQ][NQ][m][n] = __builtin_amdgcn_mfma_f32_16x16x32_bf16(            \
            AS[m][1], BS[n][1], acc[MQ][NQ][m][n], 0, 0, 0);                    \
      }                                                                         \
    __builtin_amdgcn_s_setprio(0);                                              \
  } while (0)

  f32x4 zero = {0.f, 0.f, 0.f, 0.f};
  f32x4 acc[2][2][4][2];
#pragma unroll
  for (int p = 0; p < 2; p++)
#pragma unroll
    for (int q = 0; q < 2; q++)
#pragma unroll
      for (int m = 0; m < 4; m++)
#pragma unroll
        for (int n = 0; n < 2; n++) acc[p][q][m][n] = zero;

  bf16x8 a0[4][2], a1[4][2], b0[2][2], b1[2][2];

  // prologue: tile0 (8 loads) + B(1) (4 loads); certify tile0, leave B(1).
  STG(0, 0, 0, A_,   tileM, 0);
  STG(0, 0, 1, A_,   tileM, 0);
  STG(0, 1, 0, Bt_e, tileN, 0);
  STG(0, 1, 1, Bt_e, tileN, 0);
  STG(1, 1, 0, Bt_e, tileN, 1);
  STG(1, 1, 1, Bt_e, tileN, 1);
  VM4();
  BAR();

  int cb = 0;
#pragma unroll 1
  for (int t = 0; t < 16; ++t) {
    const int nb = cb ^ 1;
    // q0 (mq0,nq0)
    RDA(cb, 0, a0); RDB(cb, 0, b0);
    if (t + 1 < 16) STG(nb, 0, 0, A_, tileM, t + 1);
    BAR(); MMQ(0, 0, a0, b0); BAR();
    // q1 (mq0,nq1)
    RDB(cb, 1, b1);
    if (t + 1 < 16) STG(nb, 0, 1, A_, tileM, t + 1);
    BAR(); MMQ(0, 1, a0, b1); BAR();
    // q2 (mq1,nq1)
    RDA(cb, 1, a1);
    if (t + 2 < 16) STG(cb, 1, 0, Bt_e, tileN, t + 2);
    BAR(); MMQ(1, 1, a1, b1); BAR();
    // q3 (mq1,nq0): a1,b0 both still live
    if (t + 2 < 16) { STG(cb, 1, 1, Bt_e, tileN, t + 2); VM4(); }
    else if (t + 1 < 16) { VM0(); }
    BAR(); MMQ(1, 0, a1, b0); BAR();
    cb = nb;
  }

  // ---------------- epilogue: LDS-staged coalesced stores ----------------
  // wave's C: rows wmi*128 + mq*64 + m*16 + fq*4 + r, cols wni*64 + nq*32 + n*16 + fr
  if (MODE == 0) {
    unsigned short* Ep = &LDS[0][0][0][0];        // [256][256] u16 = 128KB
    const int reg = tileN >> 10;                  // 0=Q,1=K,2=V (uniform)
    const bool doELU = (reg < 2);
#pragma unroll
    for (int mq = 0; mq < 2; mq++)
#pragma unroll
      for (int nq = 0; nq < 2; nq++)
#pragma unroll
        for (int m = 0; m < 4; m++)
#pragma unroll
          for (int n = 0; n < 2; n++)
#pragma unroll
            for (int r = 0; r < 4; r++) {
              int row = wmi * 128 + mq * 64 + m * 16 + fq * 4 + r;
              int col = wni * 64 + nq * 32 + n * 16 + fr;
              float v = acc[mq][nq][m][n][r];
              if (doELU) v = v > 0.f ? v : (expf(v) - 1.f);
              Ep[row * 256 + (col ^ ((row & 7) << 3))] = f2b(v);
            }
    BAR();
    unsigned short* outp = (unsigned short*)out + (size_t)reg * M_ * H_;
    const int lcbase = tileN & 1023;
#pragma unroll
    for (int it = 0; it < 16; it++) {
      int g = it * 512 + tid;          // 8192 chunks of 16B
      int row = g >> 5, col = (g & 31) * 8;
      bf16x8 val = *(const bf16x8*)&Ep[row * 256 + (col ^ ((row & 7) << 3))];
      *(bf16x8*)&outp[(size_t)(tileM + row) * H_ + lcbase + col] = val;
    }
  } else {
    float* Ef = (float*)&LDS[0][0][0][0];         // [128][256] f32 = 128KB
#pragma unroll
    for (int h = 0; h < 2; h++) {                 // tile rows h*128..h*128+127
      BAR();
      if (wmi == h) {
#pragma unroll
        for (int mq = 0; mq < 2; mq++)
#pragma unroll
          for (int nq = 0; nq < 2; nq++)
#pragma unroll
            for (int m = 0; m < 4; m++)
#pragma unroll
              for (int n = 0; n < 2; n++)
#pragma unroll
                for (int r = 0; r < 4; r++) {
                  int lr  = mq * 64 + m * 16 + fq * 4 + r;   // 0..127
                  int col = wni * 64 + nq * 32 + n * 16 + fr;
                  Ef[lr * 256 + (col ^ ((lr & 7) << 2))] = acc[mq][nq][m][n][r];
                }
      }
      BAR();
#pragma unroll
      for (int it = 0; it < 16; it++) {
        int g = it * 512 + tid;        // 8192 chunks of 16B (128 rows x 64)
        int row = g >> 6, c = (g & 63) * 4;
        f32x4 val = *(const f32x4*)&Ef[row * 256 + (c ^ ((row & 7) << 2))];
        *(f32x4*)&((float*)out)[(size_t)(tileM + h * 128 + row) * H_ + tileN + c] = val;
      }
    }
  }
#undef MMQ
#undef RDB
#undef RDA
#undef STG
}

// ---------------------------------------------------------------- stage 2: KV partials
// kvp[bh*8+ch][d][e] = sum_{s in 512-chunk} K[b,s,h,d] * V[b,s,h,e]
__global__ __launch_bounds__(256) void kv_partial(
    const unsigned short* __restrict__ Kb,
    const unsigned short* __restrict__ Vb,
    float* __restrict__ kvp) {
  __shared__ __align__(16) unsigned short kt[32 * 64];
  __shared__ __align__(16) unsigned short vt[32 * 64];
  const int bh = blockIdx.x >> 3;
  const int ch = blockIdx.x & 7;
  const int b  = bh >> 4, h = bh & 15;
  const int t  = threadIdx.x;
  const int rr = t >> 3;
  const int cc = (t & 7) * 8;
  const int d0 = (t >> 4) * 4;
  const int e0 = (t & 15) * 4;

  float acc[4][4] = {};
  for (int s0 = ch * 512; s0 < ch * 512 + 512; s0 += 32) {
    size_t g = (size_t)(b * S_ + s0 + rr) * H_ + h * 64 + cc;
    *reinterpret_cast<uint4*>(&kt[rr * 64 + cc]) = *reinterpret_cast<const uint4*>(Kb + g);
    *reinterpret_cast<uint4*>(&vt[rr * 64 + cc]) = *reinterpret_cast<const uint4*>(Vb + g);
    __syncthreads();
#pragma unroll 4
    for (int ss = 0; ss < 32; ss++) {
      ushort4 k4 = *reinterpret_cast<const ushort4*>(&kt[ss * 64 + d0]);
      ushort4 v4 = *reinterpret_cast<const ushort4*>(&vt[ss * 64 + e0]);
      float kf[4] = {b2f(k4.x), b2f(k4.y), b2f(k4.z), b2f(k4.w)};
      float vf[4] = {b2f(v4.x), b2f(v4.y), b2f(v4.z), b2f(v4.w)};
#pragma unroll
      for (int i = 0; i < 4; i++)
#pragma unroll
        for (int j = 0; j < 4; j++) acc[i][j] += kf[i] * vf[j];
    }
    __syncthreads();
  }
  float* outp = kvp + (size_t)blockIdx.x * 4096;
#pragma unroll
  for (int i = 0; i < 4; i++)
#pragma unroll
    for (int j = 0; j < 4; j++) outp[(d0 + i) * 64 + e0 + j] = acc[i][j];
}

// reduce 8 partials -> KV[bh][d][e] bf16 (row-major d)
__global__ __launch_bounds__(256) void kv_reduce(
    const float* __restrict__ kvp, unsigned short* __restrict__ KVb) {
  const int bh = blockIdx.x;
#pragma unroll
  for (int i = 0; i < 16; i++) {
    int idx = threadIdx.x + i * 256;
    float s = 0.f;
#pragma unroll
    for (int ch = 0; ch < 8; ch++) s += kvp[(size_t)(bh * 8 + ch) * 4096 + idx];
    KVb[(size_t)bh * 4096 + idx] = f2b(s);
  }
}

// ---------------------------------------------------------------- merged weight
// MbT[b][n][h*64+d] = sum_e KV[b,h][d][e] * Wo[n][h*64+e]   (Bt layout for final GEMM)
__global__ __launch_bounds__(256) void merge_m(
    const unsigned short* __restrict__ KVb,
    const unsigned short* __restrict__ Wob,
    unsigned short* __restrict__ MbT) {
  const int bh = blockIdx.x >> 2;
  const int nc = blockIdx.x & 3;
  const int b  = bh >> 4, h = bh & 15;
  const int lane = threadIdx.x & 63, wv = threadIdx.x >> 6;
  const int fr = lane & 15, fq = lane >> 4;
  const int ncb = nc * 256 + wv * 64;

  f32x4 zero = {0.f, 0.f, 0.f, 0.f};
  f32x4 acc[4][4];
#pragma unroll
  for (int i = 0; i < 4; i++)
#pragma unroll
    for (int j = 0; j < 4; j++) acc[i][j] = zero;

#pragma unroll
  for (int kk = 0; kk < 2; kk++) {
    bf16x8 af[4], bvv[4];
#pragma unroll
    for (int i = 0; i < 4; i++)
      af[i] = *(const bf16x8*)&KVb[(size_t)bh * 4096 + (i * 16 + fr) * 64 + kk * 32 + fq * 8];
#pragma unroll
    for (int j = 0; j < 4; j++)
      bvv[j] = *(const bf16x8*)&Wob[(size_t)(ncb + j * 16 + fr) * 1024 + h * 64 + kk * 32 + fq * 8];
#pragma unroll
    for (int i = 0; i < 4; i++)
#pragma unroll
      for (int j = 0; j < 4; j++)
        acc[i][j] = __builtin_amdgcn_mfma_f32_16x16x32_bf16(af[i], bvv[j], acc[i][j], 0, 0, 0);
  }
#pragma unroll
  for (int i = 0; i < 4; i++)
#pragma unroll
    for (int j = 0; j < 4; j++)
#pragma unroll
      for (int r = 0; r < 4; r++) {
        int n = ncb + j * 16 + fr;
        int k = h * 64 + i * 16 + fq * 4 + r;
        MbT[((size_t)b << 20) + (size_t)n * 1024 + k] = f2b(acc[i][j][r]);
      }
}

// ---------------------------------------------------------------- launch
extern "C" void kernel_launch(void* const* d_in, const int* in_sizes, int n_in,
                              void* d_out, int out_size, void* d_ws, size_t ws_size,
                              hipStream_t stream) {
  (void)in_sizes; (void)n_in; (void)out_size; (void)ws_size;
  const float* X  = (const float*)d_in[0];
  const float* Wq = (const float*)d_in[1];
  const float* Wk = (const float*)d_in[2];
  const float* Wv = (const float*)d_in[3];
  const float* Wo = (const float*)d_in[4];

  char*  ws  = (char*)d_ws;
  size_t off = 0;
  auto alloc = [&](size_t bytes) -> char* {
    char* p = ws + off;
    off += (bytes + 255) & ~(size_t)255;
    return p;
  };
  unsigned short* Xb   = (unsigned short*)alloc((size_t)M_ * H_ * 2);
  unsigned short* Wcat = (unsigned short*)alloc((size_t)4 * H_ * H_ * 2);  // Wq|Wk|Wv|Wo
  unsigned short* QKVb = (unsigned short*)alloc((size_t)3 * M_ * H_ * 2);  // Q|K|V
  float*          kvp  = (float*)alloc((size_t)64 * 8 * 4096 * 4);
  unsigned short* KVb  = (unsigned short*)alloc((size_t)64 * 4096 * 2);
  unsigned short* MbT  = (unsigned short*)alloc((size_t)4 * H_ * H_ * 2);

  unsigned short* Qb = QKVb;
  unsigned short* Kb = QKVb + (size_t)M_ * H_;
  unsigned short* Vb = QKVb + (size_t)2 * M_ * H_;
  unsigned short* Wob = Wcat + (size_t)3 * H_ * H_;

  cast_f32_bf16<<<(M_ * H_) / 1024, 256, 0, stream>>>(X, Xb, (M_ * H_) / 4);
  cast_w4<<<(4 * H_ * H_) / 1024, 256, 0, stream>>>(Wq, Wk, Wv, Wo, Wcat);

  gemm256<0><<<768, 512, 0, stream>>>(Xb, Wcat, QKVb);   // Q,K,V (ELU on Q,K)

  kv_partial<<<512, 256, 0, stream>>>(Kb, Vb, kvp);
  kv_reduce<<<64, 256, 0, stream>>>(kvp, KVb);
  merge_m<<<256, 256, 0, stream>>>(KVb, Wob, MbT);

  gemm256<1><<<256, 512, 0, stream>>>(Qb, MbT, (float*)d_out);  // Y = Q @ M[b]^T
}

// Round 10
// 266.152 us; speedup vs baseline: 5.3138x; 1.0002x over previous
//
#include <hip/hip_runtime.h>
#include <cstdint>
#include <cstddef>

#define B_  4
#define S_  4096
#define H_  1024
#define NH_ 16
#define M_  (B_*S_)   // 16384 rows

typedef __bf16 bf16x8 __attribute__((ext_vector_type(8)));
typedef float  f32x4  __attribute__((ext_vector_type(4)));
typedef float  f32x16 __attribute__((ext_vector_type(16)));

__device__ __forceinline__ unsigned short f2b(float f) {
  union { float f; unsigned u; } v; v.f = f;
  unsigned r = v.u + 0x7FFFu + ((v.u >> 16) & 1u);
  return (unsigned short)(r >> 16);
}
__device__ __forceinline__ float b2f(unsigned short u) {
  union { unsigned u; float f; } v; v.u = ((unsigned)u) << 16;
  return v.f;
}

#define GLD16(g, l) __builtin_amdgcn_global_load_lds( \
    (const __attribute__((address_space(1))) void*)(g), \
    (__attribute__((address_space(3))) void*)(l), 16, 0, 0)

#define VM0()  asm volatile("s_waitcnt vmcnt(0)" ::: "memory")
#define BAR()  do { asm volatile("" ::: "memory"); __builtin_amdgcn_s_barrier(); \
                    asm volatile("" ::: "memory"); } while (0)

// ---------------------------------------------------------------- casts
__global__ void cast_f32_bf16(const float* __restrict__ src,
                              unsigned short* __restrict__ dst, int n4) {
  int i = blockIdx.x * blockDim.x + threadIdx.x;
  if (i >= n4) return;
  float4 f = reinterpret_cast<const float4*>(src)[i];
  ushort4 o;
  o.x = f2b(f.x); o.y = f2b(f.y); o.z = f2b(f.z); o.w = f2b(f.w);
  reinterpret_cast<ushort4*>(dst)[i] = o;
}

__global__ void cast_w4(const float* __restrict__ w0, const float* __restrict__ w1,
                        const float* __restrict__ w2, const float* __restrict__ w3,
                        unsigned short* __restrict__ dst) {
  int i = blockIdx.x * blockDim.x + threadIdx.x;      // float4 index, 1M total
  int w = i >> 18, j = i & 0x3FFFF;
  const float* src = (w == 0) ? w0 : (w == 1) ? w1 : (w == 2) ? w2 : w3;
  float4 f = reinterpret_cast<const float4*>(src)[j];
  ushort4 o;
  o.x = f2b(f.x); o.y = f2b(f.y); o.z = f2b(f.z); o.w = f2b(f.w);
  reinterpret_cast<ushort4*>(dst)[i] = o;
}

// ---------------------------------------------------------------- 128x128 GEMM
// C[M,N] = A[M,1024]*Bt[N,1024]^T. 256 thr = 4 waves (2x2), wave = 64x64 via
// 4 subtiles of 32x32 (mfma_f32_32x32x16_bf16, 16 MFMA/wave/K-tile). BK=64,
// LDS = 2 x (A 16KB + B 16KB) = 64 KiB double-buffer -> 2 blocks/CU
// (cross-block overlap = the m97 mechanism; no intra-tile barriers).
// Loop: { stage t+1 -> buf^1 (8 gld16); 16 ds_read frags(cb); 16 MFMA;
//         vmcnt(0); BAR }  (WAR-safe: nb fully consumed at t-1's barrier.)
// Swizzle: 16B-chunk index ^= (row&7) on stage-source and reads.
// MFMA C/D map (m74/m101): col = lane&31, row = (reg&3)+8*(reg>>2)+4*(lane>>5).
// A/B frag: lane holds row = lane&31, k = (lane>>5)*8 + j.
// MODE 0: N=3072, bf16 out -> Q/K/V with ELU on Q,K (grid 3072).
// MODE 1: N=1024, Bt per-batch [4][1024][1024], f32 out (grid 1024).
template<int MODE>
__global__ __launch_bounds__(256, 2) void gemm128(
    const unsigned short* __restrict__ A_,
    const unsigned short* __restrict__ Bt_,
    void* __restrict__ out) {
  __shared__ __align__(16) unsigned short LDS[2][2][8192];  // [dbuf][A|B][128*64]

  const int NTN = (MODE == 0) ? 24 : 8;
  const int nx  = gridDim.x >> 3;
  const int b2  = (blockIdx.x & 7) * nx + (blockIdx.x >> 3);  // XCD swizzle (grid%8==0)
  const int tileM = (b2 / NTN) << 7;
  const int tileN = (b2 % NTN) << 7;

  const unsigned short* Bt_e =
      (MODE == 1) ? (Bt_ + ((size_t)(tileM >> 12) << 20)) : Bt_;

  const int tid  = threadIdx.x;
  const int lane = tid & 63, wv = tid >> 6;
  const int wr   = (wv >> 1) * 64;     // wave row offset in tile
  const int wc   = (wv & 1) * 64;      // wave col offset
  const int l31  = lane & 31;
  const int hi   = lane >> 5;

  // staging: per array 1024 chunks of 16B; thread covers ci = i*256 + wv*64 + lane
  const int srb  = wv * 8 + (lane >> 3);           // row base (i adds i*32)
  const int scol = (lane & 7) ^ (lane >> 3);       // pre-swizzled col chunk

#define STG(DB, ARR, SRC, RB, TT, I) \
    GLD16((SRC) + (size_t)((RB) + (I)*32 + srb) * 1024 + (TT)*64 + scol*8, \
          &LDS[DB][ARR][(I)*2048 + wv*512])

#define STG_ALL(DB, TT) do {                                                    \
    STG(DB, 0, A_,   tileM, TT, 0); STG(DB, 0, A_,   tileM, TT, 1);             \
    STG(DB, 0, A_,   tileM, TT, 2); STG(DB, 0, A_,   tileM, TT, 3);             \
    STG(DB, 1, Bt_e, tileN, TT, 0); STG(DB, 1, Bt_e, tileN, TT, 1);             \
    STG(DB, 1, Bt_e, tileN, TT, 2); STG(DB, 1, Bt_e, tileN, TT, 3);             \
  } while (0)

  f32x16 acc[2][2];
#pragma unroll
  for (int i = 0; i < 2; i++)
#pragma unroll
    for (int j = 0; j < 2; j++)
#pragma unroll
      for (int r = 0; r < 16; r++) acc[i][j][r] = 0.f;

  bf16x8 a[2][4], b[2][4];

  // prologue: tile 0 into buf 0
  STG_ALL(0, 0);
  VM0();
  BAR();

  int cb = 0;
#pragma unroll 1
  for (int t = 0; t < 16; ++t) {
    const int nb = cb ^ 1;
    if (t < 15) STG_ALL(nb, t + 1);
#pragma unroll
    for (int si = 0; si < 2; si++)
#pragma unroll
      for (int ks = 0; ks < 4; ks++) {
        int ra = wr + si * 32 + l31;
        a[si][ks] = *(const bf16x8*)&LDS[cb][0][ra * 64 + (((ks*2 + hi) ^ (ra & 7)) * 8)];
      }
#pragma unroll
    for (int sj = 0; sj < 2; sj++)
#pragma unroll
      for (int ks = 0; ks < 4; ks++) {
        int rb = wc + sj * 32 + l31;
        b[sj][ks] = *(const bf16x8*)&LDS[cb][1][rb * 64 + (((ks*2 + hi) ^ (rb & 7)) * 8)];
      }
    __builtin_amdgcn_s_setprio(1);
#pragma unroll
    for (int si = 0; si < 2; si++)
#pragma unroll
      for (int sj = 0; sj < 2; sj++)
#pragma unroll
        for (int ks = 0; ks < 4; ks++)
          acc[si][sj] = __builtin_amdgcn_mfma_f32_32x32x16_bf16(
              a[si][ks], b[sj][ks], acc[si][sj], 0, 0, 0);
    __builtin_amdgcn_s_setprio(0);
    VM0();
    BAR();
    cb = nb;
  }

  // ---------------- epilogue: LDS-staged coalesced stores ----------------
  if (MODE == 0) {
    unsigned short* Ep = &LDS[0][0][0];           // [128][128] u16 = 32 KB
    const int reg = tileN >> 10;                  // 0=Q,1=K,2=V (uniform)
    const bool doELU = (reg < 2);
#pragma unroll
    for (int si = 0; si < 2; si++)
#pragma unroll
      for (int sj = 0; sj < 2; sj++)
#pragma unroll
        for (int r = 0; r < 16; r++) {
          int row = wr + si * 32 + (r & 3) + 8 * (r >> 2) + 4 * hi;
          int col = wc + sj * 32 + l31;
          float v = acc[si][sj][r];
          if (doELU) v = v > 0.f ? v : (expf(v) - 1.f);
          Ep[row * 128 + ((((col >> 3) ^ (row & 7)) << 3) | (col & 7))] = f2b(v);
        }
    BAR();
    unsigned short* outp = (unsigned short*)out + (size_t)reg * M_ * H_;
    const int lcbase = tileN & 1023;
#pragma unroll
    for (int it = 0; it < 8; it++) {
      int g = it * 256 + tid;          // 2048 chunks of 16B
      int row = g >> 4, cc = g & 15;
      bf16x8 val = *(const bf16x8*)&Ep[row * 128 + ((cc ^ (row & 7)) << 3)];
      *(bf16x8*)&outp[(size_t)(tileM + row) * H_ + lcbase + cc * 8] = val;
    }
  } else {
    float* Ef = (float*)&LDS[0][0][0];            // [128][128] f32 = 64 KB
#pragma unroll
    for (int si = 0; si < 2; si++)
#pragma unroll
      for (int sj = 0; sj < 2; sj++)
#pragma unroll
        for (int r = 0; r < 16; r++) {
          int row = wr + si * 32 + (r & 3) + 8 * (r >> 2) + 4 * hi;
          int col = wc + sj * 32 + l31;
          Ef[row * 128 + ((((col >> 2) ^ (row & 7)) << 2) | (col & 3))] = acc[si][sj][r];
        }
    BAR();
#pragma unroll
    for (int it = 0; it < 16; it++) {
      int g = it * 256 + tid;          // 4096 chunks of 16B
      int row = g >> 5, cc = g & 31;
      f32x4 val = *(const f32x4*)&Ef[row * 128 + ((cc ^ (row & 7)) << 2)];
      *(f32x4*)&((float*)out)[(size_t)(tileM + row) * H_ + tileN + cc * 4] = val;
    }
  }
#undef STG_ALL
#undef STG
}

// ---------------------------------------------------------------- stage 2: KV partials
// kvp[bh*8+ch][d][e] = sum_{s in 512-chunk} K[b,s,h,d] * V[b,s,h,e]
__global__ __launch_bounds__(256) void kv_partial(
    const unsigned short* __restrict__ Kb,
    const unsigned short* __restrict__ Vb,
    float* __restrict__ kvp) {
  __shared__ __align__(16) unsigned short kt[32 * 64];
  __shared__ __align__(16) unsigned short vt[32 * 64];
  const int bh = blockIdx.x >> 3;
  const int ch = blockIdx.x & 7;
  const int b  = bh >> 4, h = bh & 15;
  const int t  = threadIdx.x;
  const int rr = t >> 3;
  const int cc = (t & 7) * 8;
  const int d0 = (t >> 4) * 4;
  const int e0 = (t & 15) * 4;

  float acc[4][4] = {};
  for (int s0 = ch * 512; s0 < ch * 512 + 512; s0 += 32) {
    size_t g = (size_t)(b * S_ + s0 + rr) * H_ + h * 64 + cc;
    *reinterpret_cast<uint4*>(&kt[rr * 64 + cc]) = *reinterpret_cast<const uint4*>(Kb + g);
    *reinterpret_cast<uint4*>(&vt[rr * 64 + cc]) = *reinterpret_cast<const uint4*>(Vb + g);
    __syncthreads();
#pragma unroll 4
    for (int ss = 0; ss < 32; ss++) {
      ushort4 k4 = *reinterpret_cast<const ushort4*>(&kt[ss * 64 + d0]);
      ushort4 v4 = *reinterpret_cast<const ushort4*>(&vt[ss * 64 + e0]);
      float kf[4] = {b2f(k4.x), b2f(k4.y), b2f(k4.z), b2f(k4.w)};
      float vf[4] = {b2f(v4.x), b2f(v4.y), b2f(v4.z), b2f(v4.w)};
#pragma unroll
      for (int i = 0; i < 4; i++)
#pragma unroll
        for (int j = 0; j < 4; j++) acc[i][j] += kf[i] * vf[j];
    }
    __syncthreads();
  }
  float* outp = kvp + (size_t)blockIdx.x * 4096;
#pragma unroll
  for (int i = 0; i < 4; i++)
#pragma unroll
    for (int j = 0; j < 4; j++) outp[(d0 + i) * 64 + e0 + j] = acc[i][j];
}

// ---------------------------------------------------------------- kv_finalize
// Reduce 8 partials -> KV[bh] in LDS (bf16), then per-batch merged weight:
// MbT[b][n][h*64+d] = sum_e KV[d][e] * Wo[n][h*64+e]. One block per bh.
__global__ __launch_bounds__(256) void kv_finalize(
    const float* __restrict__ kvp,
    const unsigned short* __restrict__ Wob,
    unsigned short* __restrict__ MbT) {
  __shared__ __align__(16) unsigned short kvs[4096];
  const int bh = blockIdx.x;
  const int b  = bh >> 4, h = bh & 15;
  const int lane = threadIdx.x & 63, wv = threadIdx.x >> 6;
  const int fr = lane & 15, fq = lane >> 4;

#pragma unroll
  for (int i = 0; i < 16; i++) {
    int idx = threadIdx.x + i * 256;
    float s = 0.f;
#pragma unroll
    for (int ch = 0; ch < 8; ch++) s += kvp[(size_t)(bh * 8 + ch) * 4096 + idx];
    kvs[idx] = f2b(s);
  }
  __syncthreads();

  // wave wv covers n in [wv*256, wv*256+256), 4 sub-chunks of 64
  for (int sc = 0; sc < 4; sc++) {
    const int ncb = wv * 256 + sc * 64;
    f32x4 zero = {0.f, 0.f, 0.f, 0.f};
    f32x4 acc[4][4];
#pragma unroll
    for (int i = 0; i < 4; i++)
#pragma unroll
      for (int j = 0; j < 4; j++) acc[i][j] = zero;
#pragma unroll
    for (int kk = 0; kk < 2; kk++) {
      bf16x8 wf[4], kf[4];
#pragma unroll
      for (int j = 0; j < 4; j++)
        wf[j] = *(const bf16x8*)&Wob[(size_t)(ncb + j * 16 + fr) * 1024 + h * 64 + kk * 32 + fq * 8];
#pragma unroll
      for (int i = 0; i < 4; i++)
        kf[i] = *(const bf16x8*)&kvs[(i * 16 + fr) * 64 + kk * 32 + fq * 8];
#pragma unroll
      for (int j = 0; j < 4; j++)
#pragma unroll
        for (int i = 0; i < 4; i++)
          acc[j][i] = __builtin_amdgcn_mfma_f32_16x16x32_bf16(wf[j], kf[i], acc[j][i], 0, 0, 0);
    }
#pragma unroll
    for (int j = 0; j < 4; j++)
#pragma unroll
      for (int i = 0; i < 4; i++)
#pragma unroll
        for (int r = 0; r < 4; r++) {
          int n = ncb + j * 16 + fq * 4 + r;
          int k = h * 64 + i * 16 + fr;
          MbT[((size_t)b << 20) + (size_t)n * 1024 + k] = f2b(acc[j][i][r]);
        }
  }
}

// ---------------------------------------------------------------- launch
extern "C" void kernel_launch(void* const* d_in, const int* in_sizes, int n_in,
                              void* d_out, int out_size, void* d_ws, size_t ws_size,
                              hipStream_t stream) {
  (void)in_sizes; (void)n_in; (void)out_size; (void)ws_size;
  const float* X  = (const float*)d_in[0];
  const float* Wq = (const float*)d_in[1];
  const float* Wk = (const float*)d_in[2];
  const float* Wv = (const float*)d_in[3];
  const float* Wo = (const float*)d_in[4];

  char*  ws  = (char*)d_ws;
  size_t off = 0;
  auto alloc = [&](size_t bytes) -> char* {
    char* p = ws + off;
    off += (bytes + 255) & ~(size_t)255;
    return p;
  };
  unsigned short* Xb   = (unsigned short*)alloc((size_t)M_ * H_ * 2);
  unsigned short* Wcat = (unsigned short*)alloc((size_t)4 * H_ * H_ * 2);  // Wq|Wk|Wv|Wo
  unsigned short* QKVb = (unsigned short*)alloc((size_t)3 * M_ * H_ * 2);  // Q|K|V
  float*          kvp  = (float*)alloc((size_t)64 * 8 * 4096 * 4);
  unsigned short* MbT  = (unsigned short*)alloc((size_t)4 * H_ * H_ * 2);

  unsigned short* Qb = QKVb;
  unsigned short* Kb = QKVb + (size_t)M_ * H_;
  unsigned short* Vb = QKVb + (size_t)2 * M_ * H_;
  unsigned short* Wob = Wcat + (size_t)3 * H_ * H_;

  cast_f32_bf16<<<(M_ * H_) / 1024, 256, 0, stream>>>(X, Xb, (M_ * H_) / 4);
  cast_w4<<<(4 * H_ * H_) / 1024, 256, 0, stream>>>(Wq, Wk, Wv, Wo, Wcat);

  gemm128<0><<<3072, 256, 0, stream>>>(Xb, Wcat, QKVb);   // Q,K,V (ELU on Q,K)

  kv_partial<<<512, 256, 0, stream>>>(Kb, Vb, kvp);
  kv_finalize<<<64, 256, 0, stream>>>(kvp, Wob, MbT);

  gemm128<1><<<1024, 256, 0, stream>>>(Qb, MbT, (float*)d_out);  // Y = Q @ M[b]^T
}